// Round 7
// baseline (288.158 us; speedup 1.0000x reference)
//
#include <hip/hip_runtime.h>

// Problem constants (from reference)
#define COLS    2048
#define CPC     32          // cells per column == 32 bits -> one word per column
#define NCELLS  65536       // COLS * CPC
#define SEGS    16
#define SYN     32
#define THRESH  13

#define PRED_BLOCKS      1024          // x 40KB LDS = exactly 4 blocks/CU, whole grid resident
#define CELLS_PER_WAVE   16            // 1024 blocks * 4 waves * 16 = 65536

// ---------------------------------------------------------------------------
// Kernel 1: active-cell phase (unchanged — correct, tiny, atomic-free).
// ---------------------------------------------------------------------------
__global__ __launch_bounds__(256) void tm_active_kernel(
    const float* __restrict__ active_columns,
    const float* __restrict__ prev_predictive,
    float* __restrict__ out_active,
    unsigned int* __restrict__ ws_mask,
    unsigned char* __restrict__ ws_flags)
{
    int n = blockIdx.x * 256 + threadIdx.x;   // cell index, grid is exact
    int c = n >> 5;                            // column
    int j = n & 31;                            // cell within column
    int lane = threadIdx.x & 63;

    bool predbit    = prev_predictive[n] > 0.0f;
    bool col_active = active_columns[c] > 0.0f;

    unsigned long long pb = __ballot(predbit);
    unsigned int colmask = (lane < 32) ? (unsigned int)pb : (unsigned int)(pb >> 32);
    bool has_pred = (colmask != 0u);

    bool active = col_active && (has_pred ? predbit : true);
    out_active[n] = active ? 1.0f : 0.0f;

    unsigned long long ab = __ballot(active);
    if (lane == 0)  ws_mask[c] = (unsigned int)ab;
    if (lane == 32) ws_mask[c] = (unsigned int)(ab >> 32);

    if (j == 0)
        ws_flags[c] = (unsigned char)((col_active ? 1 : 0) |
                                      ((col_active && has_pred) ? 2 : 0));
}

// ---------------------------------------------------------------------------
// Async global->LDS DMA, 1 KB per wave-instruction (lane i: 16 B at +i*16).
// Fire-and-forget: no result VGPRs, so the compiler cannot serialize it the
// way it serialized register-held loads in R2-R4 (the 104 us plateau).
// ---------------------------------------------------------------------------
typedef const __attribute__((address_space(1))) void* gas_ptr;
typedef __attribute__((address_space(3)))       void* las_ptr;

__device__ __forceinline__ void dma_1kb(const char* g, char* lds, int lane) {
    __builtin_amdgcn_global_load_lds((gas_ptr)(g + lane * 16), (las_ptr)lds, 16, 0, 0);
}

// s_waitcnt imms (gfx9 encoding: vmcnt[3:0] | expcnt[6:4] | lgkmcnt[11:8] |
// vmcnt_hi[15:14]; expcnt/lgkmcnt at max = don't wait):
#define WAITCNT_VM4 0x0F74   // wait until <= 4 vector-memory ops outstanding
#define WAITCNT_VM0 0x0F70   // wait until 0 outstanding

// ---------------------------------------------------------------------------
// Kernel 2: predictive phase — resident, barrier-free software pipeline.
//
// R2-R5 post-mortem: effective read rate pinned at ~4.4 B/cyc/CU across four
// designs. Shared flaw: convoy duty-cycle — each block issues, drains
// vmcnt(0) at __syncthreads, computes with the memory pipe IDLE, exits, pays
// relaunch. R6/R7 removes all idle windows:
//   * grid 1024 x 40KB LDS = exactly 4 blocks/CU, whole grid co-resident,
//     zero relaunches;
//   * each wave double-buffers its 16 cells through 2 private 4KB LDS slots:
//     issue DMAs for cell i+1, s_waitcnt vmcnt(4) (prefetch stays in
//     flight!), consume cell i — no __syncthreads in the loop, since waves
//     consume only what they themselves staged;
//   * sched_barrier(0) fences pin issue -> waitcnt -> consume order.
// Steady state: 16 waves/CU x 4KB outstanding at ~100% duty.
// vmcnt FIFO check per iter: queue = [DMA_i x4, store_{i-1}, DMA_{i+1} x4];
// vmcnt(4) retires DMA_i + old store, leaves the 4 prefetch DMAs in flight.
//
// R6 FAILED on a typo here (prologue loaded gq+3072 instead of gq+1024 ->
// garbage perms for segments 8-15 of each wave's first cell). R7 = R6 with
// that one line fixed; the pipeline experiment is otherwise unchanged.
//
// Per-cell reduction (verified R2-R5): cell = 128 int4; lane handles
// elements lane, lane+64; element e belongs to segment e/8. Pack the two
// partials, butterfly-ADD over 8 lanes, unpack+max, butterfly-MAX across
// groups, lane 0 writes.
// LDS: 8KB mask + 4 waves * 2 slots * 4KB = 40960 B.
// ---------------------------------------------------------------------------
__global__ __launch_bounds__(256) void tm_predict_kernel(
    const int*   __restrict__ seg_pre,
    const float* __restrict__ seg_perm,
    const unsigned int* __restrict__ ws_mask,
    const unsigned char* __restrict__ ws_flags,
    float* __restrict__ out_pred,
    float* __restrict__ out_anomaly)
{
    __shared__ unsigned int mask[COLS];            // 8 KB active bitmask
    __shared__ char bufs[4 * 2 * 4096];            // per-wave double buffers

    int tid  = threadIdx.x;
    int wave = tid >> 6;
    int lane = tid & 63;

    // ---- Stage the mask cooperatively, one barrier, BEFORE any DMA ----
    #pragma unroll
    for (int i = 0; i < 2; ++i)
        ((uint4*)mask)[tid + 256 * i] = ((const uint4*)ws_mask)[tid + 256 * i];
    __syncthreads();   // drains vmcnt(0) — fine, no DMAs issued yet

    int base = (blockIdx.x * 4 + wave) * CELLS_PER_WAVE;  // this wave's 16 cells
    char* mybuf = bufs + wave * 2 * 4096;

    // ---- Prologue: prefetch cell base+0 into slot 0 ----
    {
        const char* gp = (const char*)(seg_pre  + (size_t)base * 512);
        const char* gq = (const char*)(seg_perm + (size_t)base * 512);
        dma_1kb(gp,        mybuf,        lane);
        dma_1kb(gp + 1024, mybuf + 1024, lane);
        dma_1kb(gq,        mybuf + 2048, lane);
        dma_1kb(gq + 1024, mybuf + 3072, lane);   // R6's bug: was gq + 3072
    }

    #pragma unroll
    for (int i = 0; i < CELLS_PER_WAVE; ++i) {
        // ---- Prefetch cell i+1 into the other slot ----
        if (i + 1 < CELLS_PER_WAVE) {
            char* nb = mybuf + ((i + 1) & 1) * 4096;
            const char* gp = (const char*)(seg_pre  + (size_t)(base + i + 1) * 512);
            const char* gq = (const char*)(seg_perm + (size_t)(base + i + 1) * 512);
            dma_1kb(gp,        nb,        lane);
            dma_1kb(gp + 1024, nb + 1024, lane);
            dma_1kb(gq,        nb + 2048, lane);
            dma_1kb(gq + 1024, nb + 3072, lane);
        }
        __builtin_amdgcn_sched_barrier(0);
        // Wait for cell i's 4 DMAs (and any older stores); leave the 4
        // prefetch DMAs for cell i+1 in flight.
        if (i + 1 < CELLS_PER_WAVE) __builtin_amdgcn_s_waitcnt(WAITCNT_VM4);
        else                        __builtin_amdgcn_s_waitcnt(WAITCNT_VM0);
        __builtin_amdgcn_sched_barrier(0);

        // ---- Consume cell i from its slot ----
        char* sb = mybuf + (i & 1) * 4096;
        const int4*   pl = (const int4*)  sb;           // 2 KB pre
        const float4* ql = (const float4*)(sb + 2048);  // 2 KB perm

        int4   p0 = pl[lane], p1 = pl[lane + 64];
        float4 q0 = ql[lane], q1 = ql[lane + 64];

        int c0 = 0, c1 = 0;
        c0 += (q0.x >= 0.5f && ((mask[(unsigned)p0.x >> 5] >> ((unsigned)p0.x & 31u)) & 1u)) ? 1 : 0;
        c0 += (q0.y >= 0.5f && ((mask[(unsigned)p0.y >> 5] >> ((unsigned)p0.y & 31u)) & 1u)) ? 1 : 0;
        c0 += (q0.z >= 0.5f && ((mask[(unsigned)p0.z >> 5] >> ((unsigned)p0.z & 31u)) & 1u)) ? 1 : 0;
        c0 += (q0.w >= 0.5f && ((mask[(unsigned)p0.w >> 5] >> ((unsigned)p0.w & 31u)) & 1u)) ? 1 : 0;
        c1 += (q1.x >= 0.5f && ((mask[(unsigned)p1.x >> 5] >> ((unsigned)p1.x & 31u)) & 1u)) ? 1 : 0;
        c1 += (q1.y >= 0.5f && ((mask[(unsigned)p1.y >> 5] >> ((unsigned)p1.y & 31u)) & 1u)) ? 1 : 0;
        c1 += (q1.z >= 0.5f && ((mask[(unsigned)p1.z >> 5] >> ((unsigned)p1.z & 31u)) & 1u)) ? 1 : 0;
        c1 += (q1.w >= 0.5f && ((mask[(unsigned)p1.w >> 5] >> ((unsigned)p1.w & 31u)) & 1u)) ? 1 : 0;

        int v = c0 | (c1 << 16);
        v += __shfl_xor(v, 1, 64);
        v += __shfl_xor(v, 2, 64);
        v += __shfl_xor(v, 4, 64);
        int m = max(v & 0xffff, v >> 16);
        m = max(m, __shfl_xor(m, 8, 64));
        m = max(m, __shfl_xor(m, 16, 64));
        m = max(m, __shfl_xor(m, 32, 64));

        if (lane == 0)
            out_pred[base + i] = (m >= THRESH) ? 1.0f : 0.0f;
    }

    // ---- Anomaly: block 0 / wave 0 reduces 2048 flag bytes (global) ----
    if (blockIdx.x == 0 && tid < 64) {
        const unsigned int* f = (const unsigned int*)ws_flags;
        int na = 0, np = 0;
        #pragma unroll
        for (int i = 0; i < 8; ++i) {
            unsigned w = f[tid * 8 + i];
            na += __popc(w & 0x01010101u);
            np += __popc(w & 0x02020202u);
        }
        int v = na | (np << 16);
        v += __shfl_xor(v, 1, 64);
        v += __shfl_xor(v, 2, 64);
        v += __shfl_xor(v, 4, 64);
        v += __shfl_xor(v, 8, 64);
        v += __shfl_xor(v, 16, 64);
        v += __shfl_xor(v, 32, 64);
        if (tid == 0) {
            int NA = v & 0xffff, NP = v >> 16;
            *out_anomaly = 1.0f - (float)NP / (float)(NA > 1 ? NA : 1);
        }
    }
}

// ---------------------------------------------------------------------------
// Inputs (setup_inputs order):
//   d_in[0] active_columns  f32 [2048]
//   d_in[1] prev_active     f32 [65536]   (unused by the reference)
//   d_in[2] prev_predictive f32 [65536]
//   d_in[3] seg_pre         i32 [65536*16*32]
//   d_in[4] seg_perm        f32 [65536*16*32]
// Output: f32 [65536 active | 65536 predictive | 1 anomaly]
// Workspace: ws[0..2047] u32 bitmask, then 2048 u8 column flags
// ---------------------------------------------------------------------------
extern "C" void kernel_launch(void* const* d_in, const int* in_sizes, int n_in,
                              void* d_out, int out_size, void* d_ws, size_t ws_size,
                              hipStream_t stream) {
    const float* active_columns  = (const float*)d_in[0];
    const float* prev_predictive = (const float*)d_in[2];
    const int*   seg_pre         = (const int*)d_in[3];
    const float* seg_perm        = (const float*)d_in[4];
    float* out = (float*)d_out;

    unsigned int*  ws_mask  = (unsigned int*)d_ws;
    unsigned char* ws_flags = (unsigned char*)d_ws + COLS * sizeof(unsigned int);

    tm_active_kernel<<<NCELLS / 256, 256, 0, stream>>>(
        active_columns, prev_predictive, out, ws_mask, ws_flags);

    tm_predict_kernel<<<PRED_BLOCKS, 256, 0, stream>>>(
        seg_pre, seg_perm, ws_mask, ws_flags,
        out + NCELLS, out + 2 * NCELLS);
}